// Round 7
// baseline (3413.808 us; speedup 1.0000x reference)
//
#include <hip/hip_runtime.h>
#include <hip/hip_bf16.h>
#include <stdint.h>

#define N_NODES 50000
#define N_EDGES 800000
#define NH 8
#define VD 320

typedef float f32x4 __attribute__((ext_vector_type(4)));

// ---- K1: streaming edge scatter-atomic ----
// One wave64 per 4 consecutive edges (value reads are SEQUENTIAL -> full
// streaming HBM BW). Lane l covers cols [4l,4l+3]; lanes 0-15 also cover
// cols [256+4l..]. a = exp(cutoff*ew) computed inline per lane's head.
// Partial sums land in out[dst] via fp32 HW atomics: the random-RMW side is
// the 64MB output, which lives in the 256MB Infinity Cache, not HBM.
// Denominator: lanes {0,4,..,28} (first lane of each head) atomically add
// their a into s[dst,h]. softmax is shift-invariant, |cutoff*ew| <= ~6 ->
// no max pass needed (validated R1-R6: absmax 0.0078 << 0.078).
__global__ __launch_bounds__(256) void k_scatter_add(
        const float* __restrict__ value, const float* __restrict__ ew,
        const float* __restrict__ cutoff, const int* __restrict__ dst,
        float* __restrict__ out, float* __restrict__ s) {
    const int lane = threadIdx.x & 63;
    const int wid = (blockIdx.x * 256 + threadIdx.x) >> 6;
    const int c = lane * 4;
    const int h = (c < 128) ? (c >> 4) : ((c - 128) / 24);
    const bool sec = lane < 16;
    const int c2 = 256 + c;                 // secondary cols, lanes 0-15
    const int h2 = (c2 - 128) / 24;
    const bool shead = (lane < 32) && ((lane & 3) == 0);  // head = lane>>2
    size_t ebase = (size_t)wid * 4;
    #pragma unroll
    for (int i = 0; i < 4; ++i) {
        size_t e = ebase + i;
        if (e >= N_EDGES) return;           // wave-uniform guard
        int d = dst[e];
        float cu = cutoff[e];
        float a = __expf(cu * ew[e * NH + h]);
        f32x4 v = __builtin_nontemporal_load(
            reinterpret_cast<const f32x4*>(value + e * VD + c));
        float* op = out + (size_t)d * VD + c;
        unsafeAtomicAdd(op + 0, a * v.x);
        unsafeAtomicAdd(op + 1, a * v.y);
        unsafeAtomicAdd(op + 2, a * v.z);
        unsafeAtomicAdd(op + 3, a * v.w);
        if (shead) unsafeAtomicAdd(&s[(size_t)d * NH + (lane >> 2)], a);
        if (sec) {
            float a2 = __expf(cu * ew[e * NH + h2]);
            f32x4 v2 = __builtin_nontemporal_load(
                reinterpret_cast<const f32x4*>(value + e * VD + c2));
            float* op2 = out + (size_t)d * VD + c2;
            unsafeAtomicAdd(op2 + 0, a2 * v2.x);
            unsafeAtomicAdd(op2 + 1, a2 * v2.y);
            unsafeAtomicAdd(op2 + 2, a2 * v2.z);
            unsafeAtomicAdd(op2 + 3, a2 * v2.w);
        }
    }
}

// ---- K2: normalize out by per-(node,head) denominator ----
// out is L3-hot (just written by atomics); plain loads to exploit cache,
// nontemporal final store. Empty nodes: s==0 -> write 0 (matches reference).
__global__ __launch_bounds__(256) void k_norm(float* __restrict__ out,
                                              const float* __restrict__ s) {
    int i = blockIdx.x * 256 + threadIdx.x;   // f32x4 index; grid covers exactly
    int n = i / 80;
    int cg = i - n * 80;
    int c = cg * 4;
    int h = (c < 128) ? (c >> 4) : ((c - 128) / 24);
    float sv = s[(size_t)n * NH + h];
    float inv = (sv > 0.f) ? 1.0f / sv : 0.0f;
    f32x4* p = reinterpret_cast<f32x4*>(out) + i;
    f32x4 v = *p;
    v.x *= inv; v.y *= inv; v.z *= inv; v.w *= inv;
    __builtin_nontemporal_store(v, p);
}

extern "C" void kernel_launch(void* const* d_in, const int* in_sizes, int n_in,
                              void* d_out, int out_size, void* d_ws, size_t ws_size,
                              hipStream_t stream) {
    const float* value  = (const float*)d_in[0];
    const float* ew     = (const float*)d_in[1];
    const float* cutoff = (const float*)d_in[2];
    const int*   eidx   = (const int*)d_in[3];
    const int*   dst    = eidx + N_EDGES;  // edge_index[1]
    float* out = (float*)d_out;

    float* s = (float*)d_ws;               // [N_NODES*NH] denominators, 1.6 MB

    // zero accumulators (memsetAsync is graph-capture legal; runs at fill BW)
    hipMemsetAsync(out, 0, (size_t)N_NODES * VD * sizeof(float), stream);
    hipMemsetAsync(s, 0, (size_t)N_NODES * NH * sizeof(float), stream);

    // 800k edges / (4 edges/wave * 4 waves/block) = 50000 blocks
    k_scatter_add<<<50000, 256, 0, stream>>>(value, ew, cutoff, dst, out, s);
    // 50000*320/4 = 4,000,000 f32x4 elements / 256 = 15625 blocks (exact)
    k_norm<<<15625, 256, 0, stream>>>(out, s);
}

// Round 8
// 325.799 us; speedup vs baseline: 10.4783x; 10.4783x over previous
//
#include <hip/hip_runtime.h>
#include <hip/hip_bf16.h>
#include <stdint.h>

#define N_NODES 50000
#define N_EDGES 800000
#define NH 8
#define VD 320

typedef float f32x4 __attribute__((ext_vector_type(4)));

// ---- K1: degree histogram ----
__global__ __launch_bounds__(256) void k_hist(
        const int* __restrict__ dst, unsigned* __restrict__ cnt) {
    int e = blockIdx.x * 256 + threadIdx.x;
    if (e >= N_EDGES) return;
    atomicAdd(&cnt[dst[e]], 1u);
}

// ---- K2: unordered CSR range allocation (wave-scan + one atomic per wave) ----
__global__ __launch_bounds__(256) void k_ranges(
        const unsigned* __restrict__ cnt, unsigned* __restrict__ rowstart,
        unsigned* __restrict__ cursor, unsigned* __restrict__ total) {
    int i = blockIdx.x * 256 + threadIdx.x;
    int lane = threadIdx.x & 63;
    unsigned c = (i < N_NODES) ? cnt[i] : 0u;
    unsigned incl = c;
    #pragma unroll
    for (int off = 1; off < 64; off <<= 1) {
        unsigned v = __shfl_up(incl, off, 64);
        if (lane >= off) incl += v;
    }
    unsigned wave_total = __shfl(incl, 63, 64);
    unsigned base = 0;
    if (lane == 63) base = atomicAdd(total, wave_total);
    base = __shfl(base, 63, 64);
    if (i < N_NODES) {
        unsigned st = base + incl - c;
        rowstart[i] = st;
        cursor[i] = st;
    }
}

// ---- K3: scatter edge id + all-8-head exp(cutoff*ew) into CSR slots ----
// Keeps the gather's metadata reads sequential/L3-hot; value rows remain the
// only random DRAM traffic. softmax is shift-invariant, |cutoff*ew| <= ~6 ->
// no max-subtraction pass (validated R1-R7: absmax 0.0078 << 0.078).
__global__ __launch_bounds__(256) void k_scatter(
        const int* __restrict__ dst, const float* __restrict__ cutoff,
        const float* __restrict__ ew, unsigned* __restrict__ cursor,
        unsigned* __restrict__ eidArr, float* __restrict__ pexpf) {
    int e = blockIdx.x * 256 + threadIdx.x;
    if (e >= N_EDGES) return;
    float cu = cutoff[e];
    const f32x4* ewv = reinterpret_cast<const f32x4*>(ew + (size_t)e * NH);
    f32x4 w0 = ewv[0], w1 = ewv[1];
    f32x4 p0, p1;
    p0.x = __expf(cu * w0.x); p0.y = __expf(cu * w0.y);
    p0.z = __expf(cu * w0.z); p0.w = __expf(cu * w0.w);
    p1.x = __expf(cu * w1.x); p1.y = __expf(cu * w1.y);
    p1.z = __expf(cu * w1.z); p1.w = __expf(cu * w1.w);
    unsigned pos = atomicAdd(&cursor[dst[e]], 1u);
    eidArr[pos] = (unsigned)e;
    f32x4* pv = reinterpret_cast<f32x4*>(pexpf + (size_t)pos * NH);
    pv[0] = p0; pv[1] = p1;
}

// ---- K4: wave-per-node gather ----
// One wave64 owns a node. Lane l handles cols [4l,4l+3]; lanes 0-15 additionally
// cols [256+4l..]. Edge-id chunk (64) register-cached, broadcast via shfl.
// Numerators read sequentially from CSR-ordered pexpf (L1/L3-hot). Denominator
// accumulated inline; scaled once at the end. unroll-4: 4 independent 1280B
// value rows in flight per wave.
__global__ __launch_bounds__(256) void k_gather(
        const float* __restrict__ pexpf, const float* __restrict__ value,
        const unsigned* __restrict__ rowstart, const unsigned* __restrict__ cnt,
        const unsigned* __restrict__ eidArr, float* __restrict__ out) {
    int lane = threadIdx.x & 63;
    int wslot = blockIdx.x * 4 + (threadIdx.x >> 6);
    int nslots = gridDim.x * 4;
    int c = lane * 4;
    int h = (c < 128) ? (c >> 4) : ((c - 128) / 24);
    int c2 = 256 + c;                 // secondary cols, lanes 0-15 only
    int h2 = (c2 - 128) / 24;
    bool sec = lane < 16;
    for (int n = wslot; n < N_NODES; n += nslots) {
        unsigned k0 = rowstart[n];
        unsigned deg = cnt[n];
        f32x4 acc = {0.f, 0.f, 0.f, 0.f}, acc2 = {0.f, 0.f, 0.f, 0.f};
        float se = 0.f, se2 = 0.f;
        for (unsigned base = 0; base < deg; base += 64) {
            unsigned m = deg - base; if (m > 64u) m = 64u;
            unsigned pe = 0u;
            if (lane < (int)m) pe = eidArr[k0 + base + lane];
            const float* pb = pexpf + (size_t)(k0 + base) * NH;
            #pragma unroll 4
            for (unsigned j = 0; j < m; ++j) {
                unsigned e = (unsigned)__shfl((int)pe, (int)j, 64);
                float a = pb[j * NH + h];           // L1-hot sequential
                const float* vrow = value + (size_t)e * VD;
                f32x4 v = __builtin_nontemporal_load(
                    reinterpret_cast<const f32x4*>(vrow + c));
                se += a;
                acc.x += a * v.x; acc.y += a * v.y;
                acc.z += a * v.z; acc.w += a * v.w;
                if (sec) {
                    float a2 = pb[j * NH + h2];
                    f32x4 v2 = __builtin_nontemporal_load(
                        reinterpret_cast<const f32x4*>(vrow + c2));
                    se2 += a2;
                    acc2.x += a2 * v2.x; acc2.y += a2 * v2.y;
                    acc2.z += a2 * v2.z; acc2.w += a2 * v2.w;
                }
            }
        }
        float sc = (deg > 0) ? 1.0f / se : 0.0f;
        f32x4 r; r.x = acc.x * sc; r.y = acc.y * sc;
        r.z = acc.z * sc; r.w = acc.w * sc;
        __builtin_nontemporal_store(r,
            reinterpret_cast<f32x4*>(out + (size_t)n * VD + c));
        if (sec) {
            float sc2 = (deg > 0) ? 1.0f / se2 : 0.0f;
            f32x4 r2; r2.x = acc2.x * sc2; r2.y = acc2.y * sc2;
            r2.z = acc2.z * sc2; r2.w = acc2.w * sc2;
            __builtin_nontemporal_store(r2,
                reinterpret_cast<f32x4*>(out + (size_t)n * VD + c2));
        }
    }
}

extern "C" void kernel_launch(void* const* d_in, const int* in_sizes, int n_in,
                              void* d_out, int out_size, void* d_ws, size_t ws_size,
                              hipStream_t stream) {
    const float* value  = (const float*)d_in[0];
    const float* ew     = (const float*)d_in[1];
    const float* cutoff = (const float*)d_in[2];
    const int*   eidx   = (const int*)d_in[3];
    const int*   dst    = eidx + N_EDGES;  // edge_index[1]
    float* out = (float*)d_out;

    char* ws = (char*)d_ws;
    float*    pexpf    = (float*)ws;    ws += (size_t)N_EDGES * NH * 4;   // 25.6 MB, 32B-aligned
    unsigned* eidArr   = (unsigned*)ws; ws += (size_t)N_EDGES * 4;        // 3.2 MB
    unsigned* cnt      = (unsigned*)ws; ws += (size_t)((N_NODES + 3) & ~3) * 4;
    unsigned* rowstart = (unsigned*)ws; ws += (size_t)((N_NODES + 3) & ~3) * 4;
    unsigned* cursor   = (unsigned*)ws; ws += (size_t)((N_NODES + 3) & ~3) * 4;
    unsigned* total    = (unsigned*)ws; ws += 16;

    const int gE = (N_EDGES + 255) / 256;   // 3125
    const int gN = (N_NODES + 255) / 256;   // 196

    // zero cnt + total at fill-kernel speed (graph-capture legal)
    hipMemsetAsync(cnt, 0, (size_t)N_NODES * sizeof(unsigned), stream);
    hipMemsetAsync(total, 0, sizeof(unsigned), stream);

    k_hist<<<gE, 256, 0, stream>>>(dst, cnt);
    k_ranges<<<gN, 256, 0, stream>>>(cnt, rowstart, cursor, total);
    k_scatter<<<gE, 256, 0, stream>>>(dst, cutoff, ew, cursor, eidArr, pexpf);
    k_gather<<<2048, 256, 0, stream>>>(pexpf, value, rowstart, cnt, eidArr, out);
}